// Round 8
// baseline (137.478 us; speedup 1.0000x reference)
//
#include <hip/hip_runtime.h>
#include <cstdint>

#define THREADS 256
static constexpr int BS   = 4096;
static constexpr int C    = 16384;
static constexpr int D    = 128;
static constexpr int HALF = 2048;   // rows 0..2047 pair with rows 2048..4095
static constexpr int NPOS = 4;
static constexpr int NNEG = 20;
static constexpr int NSEL = 24;
static constexpr int QPT  = 16;     // int4 quads per thread (16*4 = 64 cols)

// Pre-filter: only hashes >= TH enter the per-thread top-2 (top 1/128 of u32;
// ~128 above-thresh negatives/row expected, need 20; P(shortfall) ~ e^-73).
// Selection stays EXACT: the cooperative rebuild rescans with NO threshold.
static constexpr uint32_t TH = 0xFE000000u;
// comp32 + OFF64 == full-range 64-bit comp (exact: TH's low 9 bits are 0)
static constexpr uint64_t OFF64 = ((uint64_t)(TH >> 9)) << 14;

// 1-instruction rotate: v_alignbit_b32(x,x,32-r) == rotl(x,r)
__device__ __forceinline__ uint32_t rotl32(uint32_t x, int r) {
  return __builtin_amdgcn_alignbit(x, x, 32 - r);
}

static constexpr uint32_t KS1 = 42u;
static constexpr uint32_t KS2 = 0x1BD11BDAu ^ 42u;   // ks0 = 0

// ---- JAX threefry2x32 (20 rounds), key = PRNGKey(42) = [0, 42] ----
// scalar version (cold/rebuild path)
__device__ __forceinline__ void tf2x32(uint32_t x0, uint32_t x1,
                                       uint32_t& o0, uint32_t& o1) {
  x1 += KS1;
#define TFR(r) { x0 += x1; x1 = rotl32(x1, (r)); x1 ^= x0; }
  TFR(13) TFR(15) TFR(26) TFR(6)
  x0 += KS1; x1 += KS2 + 1u;
  TFR(17) TFR(29) TFR(16) TFR(24)
  x0 += KS2; x1 += 2u;
  TFR(13) TFR(15) TFR(26) TFR(6)
  x1 += KS1 + 3u;
  TFR(17) TFR(29) TFR(16) TFR(24)
  x0 += KS1; x1 += KS2 + 4u;
  TFR(13) TFR(15) TFR(26) TFR(6)
  x0 += KS2; x1 += 5u;
#undef TFR
  o0 = x0; o1 = x1;
}

// 4-wide version: 4 independent chains interleaved round-by-round (ILP=4).
// Chain k hashes counter n+k (x1 = n+k+2^25, +ks1 folded into init).
__device__ __forceinline__ void tf4(uint32_t n, uint32_t (&oa)[4],
                                    uint32_t (&ob)[4]) {
  uint32_t x0[4], x1[4];
#pragma unroll
  for (int k = 0; k < 4; ++k) { x0[k] = n + k; x1[k] = n + k + (0x2000000u + KS1); }
#define R4(r) { _Pragma("unroll") \
  for (int k = 0; k < 4; ++k) { x0[k] += x1[k]; x1[k] = rotl32(x1[k], (r)); x1[k] ^= x0[k]; } }
#define INJ4(a0, a1) { _Pragma("unroll") \
  for (int k = 0; k < 4; ++k) { x0[k] += (a0); x1[k] += (a1); } }
  R4(13) R4(15) R4(26) R4(6)
  INJ4(KS1, KS2 + 1u)
  R4(17) R4(29) R4(16) R4(24)
  INJ4(KS2, 2u)
  R4(13) R4(15) R4(26) R4(6)
  INJ4(0u, KS1 + 3u)
  R4(17) R4(29) R4(16) R4(24)
  INJ4(KS1, KS2 + 4u)
  R4(13) R4(15) R4(26) R4(6)
  INJ4(KS2, 5u)
#undef R4
#undef INJ4
#pragma unroll
  for (int k = 0; k < 4; ++k) { oa[k] = x0[k]; ob[k] = x1[k]; }
}

// full-range 64-bit composite key (rebuild path): larger = better; equal bits
// -> smaller col wins (jax top_k tie-break). Unique per row. 0 = empty.
__device__ __forceinline__ uint64_t mkcomp(uint32_t bits, int c) {
  return (((uint64_t)(bits >> 9) + 1ull) << 14) | (uint64_t)(16383 - c);
}

// branchless thresholded u32 insert: comp32 = ((e-TH)>>9 +1)<<14 | invc if
// e>=TH else 0; then top-2 via min/max. ~10 VALU, no branches.
__device__ __forceinline__ void filt_ins(uint32_t o, int labv, uint32_t invc,
                                         uint32_t& a, uint32_t& b) {
  const uint32_t e = labv ? 0u : o;
  uint32_t comp = ((((e - TH) >> 9) + 1u) << 14) | invc;
  comp = (e >= TH) ? comp : 0u;
  const uint32_t lo = comp < a ? comp : a;
  a = comp > a ? comp : a;
  b = lo > b ? lo : b;
}

// Wave-synchronous top-20 selection for one row: one full wave, zero block
// barriers. Lane owns threads tb..tb+3, each contributing a depth-2 u32
// candidate cache (top-2 above TH). On cache exhaustion, all 64 lanes
// cooperatively rescan that thread's 64 columns (1 hash/lane + shfl max,
// NO threshold) for its next candidate strictly below the last consumed.
__device__ __forceinline__ void wave_select(
    const uint32_t (*cand)[2], int* selX, int rbase, int hi, int4 p) {
  const int lane = threadIdx.x & 63;
  const int tb = lane << 2;
  const uint64_t laneu = (uint64_t)lane;
#define CVT(x) ((x) ? (uint64_t)(x) + OFF64 : 0ull)
  uint64_t cur0 = CVT(cand[tb + 0][0]), nxt0 = CVT(cand[tb + 0][1]);
  uint64_t cur1 = CVT(cand[tb + 1][0]), nxt1 = CVT(cand[tb + 1][1]);
  uint64_t cur2 = CVT(cand[tb + 2][0]), nxt2 = CVT(cand[tb + 2][1]);
  uint64_t cur3 = CVT(cand[tb + 3][0]), nxt3 = CVT(cand[tb + 3][1]);
#undef CVT
  for (int it = 0; it < NNEG; ++it) {
    uint64_t m = (cur0 << 8) | laneu;
    uint64_t t = (cur1 << 8) | 0x40ull | laneu; if (t > m) m = t;
    t = (cur2 << 8) | 0x80ull | laneu;          if (t > m) m = t;
    t = (cur3 << 8) | 0xC0ull | laneu;          if (t > m) m = t;
#pragma unroll
    for (int o = 32; o; o >>= 1) {
      const uint64_t y = (uint64_t)__shfl_xor((unsigned long long)m, o, 64);
      if (y > m) m = y;
    }
    if (lane == 0) selX[NPOS + it] = 16383 - (int)((m >> 8) & 0x3FFFull);
    const int owner = (int)(m & 63ull);
    const int slot  = (int)((m >> 6) & 3ull);
    const uint64_t bound = m >> 8;
    const uint64_t mynxt = slot == 0 ? nxt0 : slot == 1 ? nxt1
                         : slot == 2 ? nxt2 : nxt3;
    const uint64_t ownnxt =
        (uint64_t)__shfl((unsigned long long)mynxt, owner, 64);
    if (ownnxt) {                       // wave-uniform branch
      if (lane == owner) {
        if      (slot == 0) { cur0 = ownnxt; nxt0 = 0; }
        else if (slot == 1) { cur1 = ownnxt; nxt1 = 0; }
        else if (slot == 2) { cur2 = ownnxt; nxt2 = 0; }
        else                { cur3 = ownnxt; nxt3 = 0; }
      }
    } else {                            // cooperative rebuild (rare)
      const int thr = (owner << 2) | slot;
      const int col = (((lane >> 2) * THREADS + thr) << 2) + (lane & 3);
      uint32_t o0, o1;
      tf2x32((uint32_t)(rbase + col), (uint32_t)(rbase + col) + 0x2000000u, o0, o1);
      uint64_t v = mkcomp(hi ? o1 : o0, col);
      if (col == p.x || col == p.y || col == p.z || col == p.w || v >= bound)
        v = 0;
#pragma unroll
      for (int o = 32; o; o >>= 1) {
        const uint64_t y = (uint64_t)__shfl_xor((unsigned long long)v, o, 64);
        if (y > v) v = y;
      }
      if (lane == owner) {
        if      (slot == 0) cur0 = v;
        else if (slot == 1) cur1 = v;
        else if (slot == 2) cur2 = v;
        else                cur3 = v;
      }
    }
  }
}

// ---- single fused kernel: stream labels + hash + select + sim + BCE ----
__global__ __launch_bounds__(THREADS, 2) void supcon_fused(
    const float* __restrict__ feat, const float* __restrict__ proto,
    const int* __restrict__ lab, float* __restrict__ row_ws) {
  __shared__ uint32_t candL[THREADS][2];
  __shared__ uint32_t candH[THREADS][2];
  __shared__ int selL[NSEL], selH[NSEL];
  __shared__ int posCnt[2];
  __shared__ int posBuf[2][4];
  __shared__ float ffL[D], ffH[D];
  __shared__ float normL, normH;
  __shared__ float bces[2 * NSEL];

  const int tid = threadIdx.x;
  const int r = blockIdx.x;            // low row; pairs with r+HALF
  const int rbase = r * C;             // threefry x0 base (< 2^25)

  if (tid < 2) posCnt[tid] = 0;
  __syncthreads();

  // ---- Phase A: stream both label rows (rolling prefetch); 4-wide hash;
  //      fully branchless thresholded top-2 insert (u32). The only branches
  //      in the loop are the rare (~6%-taken) positive-capture guards.
  const int4* labL4 = reinterpret_cast<const int4*>(lab + (size_t)rbase);
  const int4* labH4 = reinterpret_cast<const int4*>(lab + ((size_t)r + HALF) * C);
  uint32_t L0 = 0, L1 = 0, H0 = 0, H1 = 0;
  int4 lL = labL4[tid];
  int4 lH = labH4[tid];
  for (int j = 0; j < QPT; ++j) {
    int4 nL = lL, nH = lH;
    if (j + 1 < QPT) {                  // prefetch next quad pair
      nL = labL4[(j + 1) * THREADS + tid];
      nH = labH4[(j + 1) * THREADS + tid];
    }
    const int cq = (j * THREADS + tid) << 2;
    // rare positive capture (per-side P ~ 6% per wave-iter)
    if (lL.x | lL.y | lL.z | lL.w) {
      if (lL.x) { int s = atomicAdd(&posCnt[0], 1); if (s < 4) posBuf[0][s] = cq; }
      if (lL.y) { int s = atomicAdd(&posCnt[0], 1); if (s < 4) posBuf[0][s] = cq + 1; }
      if (lL.z) { int s = atomicAdd(&posCnt[0], 1); if (s < 4) posBuf[0][s] = cq + 2; }
      if (lL.w) { int s = atomicAdd(&posCnt[0], 1); if (s < 4) posBuf[0][s] = cq + 3; }
    }
    if (lH.x | lH.y | lH.z | lH.w) {
      if (lH.x) { int s = atomicAdd(&posCnt[1], 1); if (s < 4) posBuf[1][s] = cq; }
      if (lH.y) { int s = atomicAdd(&posCnt[1], 1); if (s < 4) posBuf[1][s] = cq + 1; }
      if (lH.z) { int s = atomicAdd(&posCnt[1], 1); if (s < 4) posBuf[1][s] = cq + 2; }
      if (lH.w) { int s = atomicAdd(&posCnt[1], 1); if (s < 4) posBuf[1][s] = cq + 3; }
    }
    uint32_t oa[4], ob[4];
    tf4((uint32_t)(rbase + cq), oa, ob);
    const uint32_t invq = 16383u - (uint32_t)cq;
    filt_ins(oa[0], lL.x, invq,      L0, L1);
    filt_ins(oa[1], lL.y, invq - 1u, L0, L1);
    filt_ins(oa[2], lL.z, invq - 2u, L0, L1);
    filt_ins(oa[3], lL.w, invq - 3u, L0, L1);
    filt_ins(ob[0], lH.x, invq,      H0, H1);
    filt_ins(ob[1], lH.y, invq - 1u, H0, H1);
    filt_ins(ob[2], lH.z, invq - 2u, H0, H1);
    filt_ins(ob[3], lH.w, invq - 3u, H0, H1);
    lL = nL; lH = nH;
  }
  candL[tid][0] = L0; candL[tid][1] = L1;
  candH[tid][0] = H0; candH[tid][1] = H1;
  __syncthreads();

  if (tid < 2) {   // sort the 4 positive cols ascending (jax top_k tie order)
    int a = posBuf[tid][0], b = posBuf[tid][1], c2 = posBuf[tid][2], d = posBuf[tid][3];
#define CSW(x, y) if (x > y) { int t_ = x; x = y; y = t_; }
    CSW(a, b) CSW(c2, d) CSW(a, c2) CSW(b, d) CSW(b, c2)
#undef CSW
    int* s = tid ? selH : selL;
    s[0] = a; s[1] = b; s[2] = c2; s[3] = d;
  }
  __syncthreads();

  // ---- Phase B: wave 0 selects L negs, wave 1 selects H negs,
  //      waves 2/3 load + normalize the two feature rows. No barriers inside.
  const int wv = tid >> 6;
  if (wv == 0) {
    const int4 p = { selL[0], selL[1], selL[2], selL[3] };
    wave_select(candL, selL, rbase, 0, p);
  } else if (wv == 1) {
    const int4 p = { selH[0], selH[1], selH[2], selH[3] };
    wave_select(candH, selH, rbase, 1, p);
  } else if (wv == 2) {
    const int l = tid & 63;
    const float a = feat[(size_t)r * D + l];
    const float b = feat[(size_t)r * D + 64 + l];
    ffL[l] = a; ffL[64 + l] = b;
    float s = a * a + b * b;
#pragma unroll
    for (int o = 32; o; o >>= 1) s += __shfl_xor(s, o, 64);
    if (l == 0) normL = s;
  } else {
    const int l = tid & 63;
    const float a = feat[((size_t)r + HALF) * D + l];
    const float b = feat[((size_t)r + HALF) * D + 64 + l];
    ffH[l] = a; ffH[64 + l] = b;
    float s = a * a + b * b;
#pragma unroll
    for (int o = 32; o; o >>= 1) s += __shfl_xor(s, o, 64);
    if (l == 0) normH = s;
  }
  __syncthreads();

  // ---- Phase C: 48 selected columns x 4 lanes each -> sim + BCE ----
  if (tid < 4 * 2 * NSEL) {
    const int ci = tid >> 2;            // 0..47
    const int k  = tid & 3;
    const bool isH = ci >= NSEL;
    const int g = isH ? ci - NSEL : ci;
    const int c = isH ? selH[g] : selL[g];
    const float* ff = isH ? ffH : ffL;
    const float4* pc = reinterpret_cast<const float4*>(proto + (size_t)c * D);
    float fp = 0.f, pp = 0.f;
#pragma unroll
    for (int qq = 0; qq < 8; ++qq) {
      const float4 pv = pc[k * 8 + qq];
      const int d0 = k * 32 + qq * 4;
      fp += ff[d0] * pv.x + ff[d0 + 1] * pv.y + ff[d0 + 2] * pv.z + ff[d0 + 3] * pv.w;
      pp += pv.x * pv.x + pv.y * pv.y + pv.z * pv.z + pv.w * pv.w;
    }
    fp += __shfl_xor(fp, 1, 64); pp += __shfl_xor(pp, 1, 64);
    fp += __shfl_xor(fp, 2, 64); pp += __shfl_xor(pp, 2, 64);
    if (k == 0) {
      const float x = (isH ? normH : normL) * pp;
      float rn = rsqrtf(x);
      rn = rn * (1.5f - 0.5f * x * rn * rn);   // 1 NR step for accuracy
      const float l = fp * rn * 10.0f;          // /TEMP, TEMP=0.1
      const float tgt = (g < NPOS) ? 0.25f : 0.0f;
      bces[ci] = fmaxf(l, 0.f) - l * tgt + __logf(1.0f + __expf(-fabsf(l)));
    }
  }
  __syncthreads();
  if (tid < 2) {
    float s = 0.f;
    const int base = tid * NSEL;
#pragma unroll
    for (int i = 0; i < NSEL; ++i) s += bces[base + i];
    row_ws[tid ? (r + HALF) : r] = s * (1.0f / NSEL);
  }
}

__global__ __launch_bounds__(THREADS) void supcon_reduce(
    const float* __restrict__ ws, float* __restrict__ out) {
  __shared__ float red[THREADS];
  const int tid = threadIdx.x;
  float s = 0.f;
#pragma unroll
  for (int j = 0; j < BS / THREADS; ++j) s += ws[j * THREADS + tid];
  red[tid] = s;
  __syncthreads();
  for (int o = THREADS / 2; o > 0; o >>= 1) {
    if (tid < o) red[tid] += red[tid + o];
    __syncthreads();
  }
  if (tid == 0) out[0] = red[0] * (1.0f / BS);
}

extern "C" void kernel_launch(void* const* d_in, const int* in_sizes, int n_in,
                              void* d_out, int out_size, void* d_ws, size_t ws_size,
                              hipStream_t stream) {
  (void)in_sizes; (void)n_in; (void)out_size; (void)ws_size;
  const float* feat  = (const float*)d_in[0];
  const float* proto = (const float*)d_in[1];
  const int*   lab   = (const int*)d_in[2];
  float* out = (float*)d_out;
  float* ws  = (float*)d_ws;   // [0..4095]: per-row mean-BCE

  supcon_fused<<<dim3(HALF), dim3(THREADS), 0, stream>>>(feat, proto, lab, ws);
  supcon_reduce<<<dim3(1), dim3(THREADS), 0, stream>>>(ws, out);
}

// Round 9
// 121.299 us; speedup vs baseline: 1.1334x; 1.1334x over previous
//
#include <hip/hip_runtime.h>
#include <cstdint>

#define THREADS 256
static constexpr int BS   = 4096;
static constexpr int C    = 16384;
static constexpr int D    = 128;
static constexpr int HALF = 2048;   // rows 0..2047 pair with rows 2048..4095
static constexpr int NPOS = 4;
static constexpr int NNEG = 20;
static constexpr int NSEL = 24;
static constexpr int QPT  = 16;     // int4 quads per thread (16*4 = 64 cols)

// Pre-filter: only hashes >= TH enter the per-thread top-2 (top 1/128 of u32;
// ~128 above-thresh negatives/row expected, need 20; P(shortfall) ~ e^-73).
// Selection stays EXACT: the cooperative rebuild rescans with NO threshold.
static constexpr uint32_t TH = 0xFE000000u;
// comp32 + OFF64 == full-range 64-bit comp (exact: TH's low 9 bits are 0)
static constexpr uint64_t OFF64 = ((uint64_t)(TH >> 9)) << 14;

// 1-instruction rotate: v_alignbit_b32(x,x,32-r) == rotl(x,r)
__device__ __forceinline__ uint32_t rotl32(uint32_t x, int r) {
  return __builtin_amdgcn_alignbit(x, x, 32 - r);
}

static constexpr uint32_t KS1 = 42u;
static constexpr uint32_t KS2 = 0x1BD11BDAu ^ 42u;   // ks0 = 0

// ---- JAX threefry2x32 (20 rounds), key = PRNGKey(42) = [0, 42] ----
// scalar version (cold/rebuild path)
__device__ __forceinline__ void tf2x32(uint32_t x0, uint32_t x1,
                                       uint32_t& o0, uint32_t& o1) {
  x1 += KS1;
#define TFR(r) { x0 += x1; x1 = rotl32(x1, (r)); x1 ^= x0; }
  TFR(13) TFR(15) TFR(26) TFR(6)
  x0 += KS1; x1 += KS2 + 1u;
  TFR(17) TFR(29) TFR(16) TFR(24)
  x0 += KS2; x1 += 2u;
  TFR(13) TFR(15) TFR(26) TFR(6)
  x1 += KS1 + 3u;
  TFR(17) TFR(29) TFR(16) TFR(24)
  x0 += KS1; x1 += KS2 + 4u;
  TFR(13) TFR(15) TFR(26) TFR(6)
  x0 += KS2; x1 += 5u;
#undef TFR
  o0 = x0; o1 = x1;
}

// 4-wide version: 4 independent chains interleaved round-by-round (ILP=4).
// Chain k hashes counter n+k (x1 = n+k+2^25, +ks1 folded into init).
__device__ __forceinline__ void tf4(uint32_t n, uint32_t (&oa)[4],
                                    uint32_t (&ob)[4]) {
  uint32_t x0[4], x1[4];
#pragma unroll
  for (int k = 0; k < 4; ++k) { x0[k] = n + k; x1[k] = n + k + (0x2000000u + KS1); }
#define R4(r) { _Pragma("unroll") \
  for (int k = 0; k < 4; ++k) { x0[k] += x1[k]; x1[k] = rotl32(x1[k], (r)); x1[k] ^= x0[k]; } }
#define INJ4(a0, a1) { _Pragma("unroll") \
  for (int k = 0; k < 4; ++k) { x0[k] += (a0); x1[k] += (a1); } }
  R4(13) R4(15) R4(26) R4(6)
  INJ4(KS1, KS2 + 1u)
  R4(17) R4(29) R4(16) R4(24)
  INJ4(KS2, 2u)
  R4(13) R4(15) R4(26) R4(6)
  INJ4(0u, KS1 + 3u)
  R4(17) R4(29) R4(16) R4(24)
  INJ4(KS1, KS2 + 4u)
  R4(13) R4(15) R4(26) R4(6)
  INJ4(KS2, 5u)
#undef R4
#undef INJ4
#pragma unroll
  for (int k = 0; k < 4; ++k) { oa[k] = x0[k]; ob[k] = x1[k]; }
}

// full-range 64-bit composite key (rebuild path): larger = better; equal bits
// -> smaller col wins (jax top_k tie-break). Unique per row. 0 = empty.
__device__ __forceinline__ uint64_t mkcomp(uint32_t bits, int c) {
  return (((uint64_t)(bits >> 9) + 1ull) << 14) | (uint64_t)(16383 - c);
}

// branchless thresholded u32 insert: comp32 = ((e-TH)>>9 +1)<<14 | invc if
// e>=TH else 0; then top-2 via min/max. ~11 VALU, no branches.
__device__ __forceinline__ void filt_ins(uint32_t o, int labv, uint32_t invc,
                                         uint32_t& a, uint32_t& b) {
  const uint32_t e = labv ? 0u : o;
  uint32_t comp = ((((e - TH) >> 9) + 1u) << 14) | invc;
  comp = (e >= TH) ? comp : 0u;
  const uint32_t lo = comp < a ? comp : a;
  a = comp > a ? comp : a;
  b = lo > b ? lo : b;
}

// Wave-synchronous top-20 selection for one row: one full wave, zero block
// barriers. Lane owns threads tb..tb+3, each contributing a depth-2 u32
// candidate cache (top-2 above TH). On cache exhaustion, all 64 lanes
// cooperatively rescan that thread's 64 columns (1 hash/lane + shfl max,
// NO threshold) for its next candidate strictly below the last consumed.
__device__ __forceinline__ void wave_select(
    const uint32_t (*cand)[2], int* selX, int rbase, int hi, int4 p) {
  const int lane = threadIdx.x & 63;
  const int tb = lane << 2;
  const uint64_t laneu = (uint64_t)lane;
#define CVT(x) ((x) ? (uint64_t)(x) + OFF64 : 0ull)
  uint64_t cur0 = CVT(cand[tb + 0][0]), nxt0 = CVT(cand[tb + 0][1]);
  uint64_t cur1 = CVT(cand[tb + 1][0]), nxt1 = CVT(cand[tb + 1][1]);
  uint64_t cur2 = CVT(cand[tb + 2][0]), nxt2 = CVT(cand[tb + 2][1]);
  uint64_t cur3 = CVT(cand[tb + 3][0]), nxt3 = CVT(cand[tb + 3][1]);
#undef CVT
  for (int it = 0; it < NNEG; ++it) {
    uint64_t m = (cur0 << 8) | laneu;
    uint64_t t = (cur1 << 8) | 0x40ull | laneu; if (t > m) m = t;
    t = (cur2 << 8) | 0x80ull | laneu;          if (t > m) m = t;
    t = (cur3 << 8) | 0xC0ull | laneu;          if (t > m) m = t;
#pragma unroll
    for (int o = 32; o; o >>= 1) {
      const uint64_t y = (uint64_t)__shfl_xor((unsigned long long)m, o, 64);
      if (y > m) m = y;
    }
    if (lane == 0) selX[NPOS + it] = 16383 - (int)((m >> 8) & 0x3FFFull);
    const int owner = (int)(m & 63ull);
    const int slot  = (int)((m >> 6) & 3ull);
    const uint64_t bound = m >> 8;
    const uint64_t mynxt = slot == 0 ? nxt0 : slot == 1 ? nxt1
                         : slot == 2 ? nxt2 : nxt3;
    const uint64_t ownnxt =
        (uint64_t)__shfl((unsigned long long)mynxt, owner, 64);
    if (ownnxt) {                       // wave-uniform branch
      if (lane == owner) {
        if      (slot == 0) { cur0 = ownnxt; nxt0 = 0; }
        else if (slot == 1) { cur1 = ownnxt; nxt1 = 0; }
        else if (slot == 2) { cur2 = ownnxt; nxt2 = 0; }
        else                { cur3 = ownnxt; nxt3 = 0; }
      }
    } else {                            // cooperative rebuild (rare)
      const int thr = (owner << 2) | slot;
      const int col = (((lane >> 2) * THREADS + thr) << 2) + (lane & 3);
      uint32_t o0, o1;
      tf2x32((uint32_t)(rbase + col), (uint32_t)(rbase + col) + 0x2000000u, o0, o1);
      uint64_t v = mkcomp(hi ? o1 : o0, col);
      if (col == p.x || col == p.y || col == p.z || col == p.w || v >= bound)
        v = 0;
#pragma unroll
      for (int o = 32; o; o >>= 1) {
        const uint64_t y = (uint64_t)__shfl_xor((unsigned long long)v, o, 64);
        if (y > v) v = y;
      }
      if (lane == owner) {
        if      (slot == 0) cur0 = v;
        else if (slot == 1) cur1 = v;
        else if (slot == 2) cur2 = v;
        else                cur3 = v;
      }
    }
  }
}

// ---- single fused kernel: stream labels + hash + select + sim + BCE ----
__global__ __launch_bounds__(THREADS, 2) void supcon_fused(
    const float* __restrict__ feat, const float* __restrict__ proto,
    const int* __restrict__ lab, float* __restrict__ row_ws) {
  __shared__ uint32_t candL[THREADS][2];
  __shared__ uint32_t candH[THREADS][2];
  __shared__ int selL[NSEL], selH[NSEL];
  __shared__ int posCnt[2];
  __shared__ int posBuf[2][4];
  __shared__ float ffL[D], ffH[D];
  __shared__ float normL, normH;
  __shared__ float bces[2 * NSEL];

  const int tid = threadIdx.x;
  const int r = blockIdx.x;            // low row; pairs with r+HALF
  const int rbase = r * C;             // threefry x0 base (< 2^25)

  if (tid < 2) posCnt[tid] = 0;
  __syncthreads();

  // ---- Phase A: stream both label rows; 4-wide hash; branchless top-2.
  //      COMPACT loop (unroll 1, 2 quads/iter, distance-2 prefetch): the
  //      fully-unrolled version is ~50 KB of straight-line code and thrashes
  //      the CU instruction cache; this body is ~6 KB and resident.
  const int4* labL4 = reinterpret_cast<const int4*>(lab + (size_t)rbase);
  const int4* labH4 = reinterpret_cast<const int4*>(lab + ((size_t)r + HALF) * C);
  uint32_t L0 = 0, L1 = 0, H0 = 0, H1 = 0;
  int4 cL0 = labL4[tid],           cH0 = labH4[tid];
  int4 cL1 = labL4[THREADS + tid], cH1 = labH4[THREADS + tid];

#define PROC(JQ, LV, HV) {                                                     \
    const int cq = ((JQ) * THREADS + tid) << 2;                                \
    if (LV.x | LV.y | LV.z | LV.w) {                                           \
      if (LV.x) { int s = atomicAdd(&posCnt[0], 1); if (s < 4) posBuf[0][s] = cq; }     \
      if (LV.y) { int s = atomicAdd(&posCnt[0], 1); if (s < 4) posBuf[0][s] = cq + 1; } \
      if (LV.z) { int s = atomicAdd(&posCnt[0], 1); if (s < 4) posBuf[0][s] = cq + 2; } \
      if (LV.w) { int s = atomicAdd(&posCnt[0], 1); if (s < 4) posBuf[0][s] = cq + 3; } \
    }                                                                          \
    if (HV.x | HV.y | HV.z | HV.w) {                                           \
      if (HV.x) { int s = atomicAdd(&posCnt[1], 1); if (s < 4) posBuf[1][s] = cq; }     \
      if (HV.y) { int s = atomicAdd(&posCnt[1], 1); if (s < 4) posBuf[1][s] = cq + 1; } \
      if (HV.z) { int s = atomicAdd(&posCnt[1], 1); if (s < 4) posBuf[1][s] = cq + 2; } \
      if (HV.w) { int s = atomicAdd(&posCnt[1], 1); if (s < 4) posBuf[1][s] = cq + 3; } \
    }                                                                          \
    uint32_t oa[4], ob[4];                                                     \
    tf4((uint32_t)(rbase + cq), oa, ob);                                       \
    const uint32_t invq = 16383u - (uint32_t)cq;                               \
    filt_ins(oa[0], LV.x, invq,      L0, L1);                                  \
    filt_ins(oa[1], LV.y, invq - 1u, L0, L1);                                  \
    filt_ins(oa[2], LV.z, invq - 2u, L0, L1);                                  \
    filt_ins(oa[3], LV.w, invq - 3u, L0, L1);                                  \
    filt_ins(ob[0], HV.x, invq,      H0, H1);                                  \
    filt_ins(ob[1], HV.y, invq - 1u, H0, H1);                                  \
    filt_ins(ob[2], HV.z, invq - 2u, H0, H1);                                  \
    filt_ins(ob[3], HV.w, invq - 3u, H0, H1); }

#pragma unroll 1
  for (int j = 0; j < QPT; j += 2) {
    int4 nL0 = cL0, nH0 = cH0, nL1 = cL1, nH1 = cH1;
    if (j + 2 < QPT) {                  // distance-2 prefetch
      nL0 = labL4[(j + 2) * THREADS + tid]; nH0 = labH4[(j + 2) * THREADS + tid];
      nL1 = labL4[(j + 3) * THREADS + tid]; nH1 = labH4[(j + 3) * THREADS + tid];
    }
    PROC(j,     cL0, cH0)
    PROC(j + 1, cL1, cH1)
    cL0 = nL0; cH0 = nH0; cL1 = nL1; cH1 = nH1;
  }
#undef PROC

  candL[tid][0] = L0; candL[tid][1] = L1;
  candH[tid][0] = H0; candH[tid][1] = H1;
  __syncthreads();

  if (tid < 2) {   // sort the 4 positive cols ascending (jax top_k tie order)
    int a = posBuf[tid][0], b = posBuf[tid][1], c2 = posBuf[tid][2], d = posBuf[tid][3];
#define CSW(x, y) if (x > y) { int t_ = x; x = y; y = t_; }
    CSW(a, b) CSW(c2, d) CSW(a, c2) CSW(b, d) CSW(b, c2)
#undef CSW
    int* s = tid ? selH : selL;
    s[0] = a; s[1] = b; s[2] = c2; s[3] = d;
  }
  __syncthreads();

  // ---- Phase B: wave 0 selects L negs, wave 1 selects H negs,
  //      waves 2/3 load + normalize the two feature rows. No barriers inside.
  const int wv = tid >> 6;
  if (wv == 0) {
    const int4 p = { selL[0], selL[1], selL[2], selL[3] };
    wave_select(candL, selL, rbase, 0, p);
  } else if (wv == 1) {
    const int4 p = { selH[0], selH[1], selH[2], selH[3] };
    wave_select(candH, selH, rbase, 1, p);
  } else if (wv == 2) {
    const int l = tid & 63;
    const float a = feat[(size_t)r * D + l];
    const float b = feat[(size_t)r * D + 64 + l];
    ffL[l] = a; ffL[64 + l] = b;
    float s = a * a + b * b;
#pragma unroll
    for (int o = 32; o; o >>= 1) s += __shfl_xor(s, o, 64);
    if (l == 0) normL = s;
  } else {
    const int l = tid & 63;
    const float a = feat[((size_t)r + HALF) * D + l];
    const float b = feat[((size_t)r + HALF) * D + 64 + l];
    ffH[l] = a; ffH[64 + l] = b;
    float s = a * a + b * b;
#pragma unroll
    for (int o = 32; o; o >>= 1) s += __shfl_xor(s, o, 64);
    if (l == 0) normH = s;
  }
  __syncthreads();

  // ---- Phase C: 48 selected columns x 4 lanes each -> sim + BCE ----
  if (tid < 4 * 2 * NSEL) {
    const int ci = tid >> 2;            // 0..47
    const int k  = tid & 3;
    const bool isH = ci >= NSEL;
    const int g = isH ? ci - NSEL : ci;
    const int c = isH ? selH[g] : selL[g];
    const float* ff = isH ? ffH : ffL;
    const float4* pc = reinterpret_cast<const float4*>(proto + (size_t)c * D);
    float fp = 0.f, pp = 0.f;
#pragma unroll
    for (int qq = 0; qq < 8; ++qq) {
      const float4 pv = pc[k * 8 + qq];
      const int d0 = k * 32 + qq * 4;
      fp += ff[d0] * pv.x + ff[d0 + 1] * pv.y + ff[d0 + 2] * pv.z + ff[d0 + 3] * pv.w;
      pp += pv.x * pv.x + pv.y * pv.y + pv.z * pv.z + pv.w * pv.w;
    }
    fp += __shfl_xor(fp, 1, 64); pp += __shfl_xor(pp, 1, 64);
    fp += __shfl_xor(fp, 2, 64); pp += __shfl_xor(pp, 2, 64);
    if (k == 0) {
      const float x = (isH ? normH : normL) * pp;
      float rn = rsqrtf(x);
      rn = rn * (1.5f - 0.5f * x * rn * rn);   // 1 NR step for accuracy
      const float l = fp * rn * 10.0f;          // /TEMP, TEMP=0.1
      const float tgt = (g < NPOS) ? 0.25f : 0.0f;
      bces[ci] = fmaxf(l, 0.f) - l * tgt + __logf(1.0f + __expf(-fabsf(l)));
    }
  }
  __syncthreads();
  if (tid < 2) {
    float s = 0.f;
    const int base = tid * NSEL;
#pragma unroll
    for (int i = 0; i < NSEL; ++i) s += bces[base + i];
    row_ws[tid ? (r + HALF) : r] = s * (1.0f / NSEL);
  }
}

__global__ __launch_bounds__(THREADS) void supcon_reduce(
    const float* __restrict__ ws, float* __restrict__ out) {
  __shared__ float red[THREADS];
  const int tid = threadIdx.x;
  float s = 0.f;
#pragma unroll
  for (int j = 0; j < BS / THREADS; ++j) s += ws[j * THREADS + tid];
  red[tid] = s;
  __syncthreads();
  for (int o = THREADS / 2; o > 0; o >>= 1) {
    if (tid < o) red[tid] += red[tid + o];
    __syncthreads();
  }
  if (tid == 0) out[0] = red[0] * (1.0f / BS);
}

extern "C" void kernel_launch(void* const* d_in, const int* in_sizes, int n_in,
                              void* d_out, int out_size, void* d_ws, size_t ws_size,
                              hipStream_t stream) {
  (void)in_sizes; (void)n_in; (void)out_size; (void)ws_size;
  const float* feat  = (const float*)d_in[0];
  const float* proto = (const float*)d_in[1];
  const int*   lab   = (const int*)d_in[2];
  float* out = (float*)d_out;
  float* ws  = (float*)d_ws;   // [0..4095]: per-row mean-BCE

  supcon_fused<<<dim3(HALF), dim3(THREADS), 0, stream>>>(feat, proto, lab, ws);
  supcon_reduce<<<dim3(1), dim3(THREADS), 0, stream>>>(ws, out);
}

// Round 10
// 117.514 us; speedup vs baseline: 1.1699x; 1.0322x over previous
//
#include <hip/hip_runtime.h>
#include <cstdint>

#define THREADS 256
static constexpr int BS   = 4096;
static constexpr int C    = 16384;
static constexpr int D    = 128;
static constexpr int HALF = 2048;   // rows 0..2047 pair with rows 2048..4095
static constexpr int NPOS = 4;
static constexpr int NNEG = 20;
static constexpr int NSEL = 24;
static constexpr int QPT  = 16;     // int4 quads per thread (16*4 = 64 cols)

// Pre-filter: only hashes >= TH enter the per-thread top-2 (top 1/128 of u32;
// ~128 above-thresh candidates/row expected, need <=24; P(shortfall) ~ 0).
// Selection stays EXACT: the cooperative rebuild rescans with NO threshold.
static constexpr uint32_t TH = 0xFE000000u;
// comp32 + OFF64 == full-range 64-bit comp (exact: TH's low 9 bits are 0)
static constexpr uint64_t OFF64 = ((uint64_t)(TH >> 9)) << 14;

// 1-instruction rotate: v_alignbit_b32(x,x,32-r) == rotl(x,r)
__device__ __forceinline__ uint32_t rotl32(uint32_t x, int r) {
  return __builtin_amdgcn_alignbit(x, x, 32 - r);
}

static constexpr uint32_t KS1 = 42u;
static constexpr uint32_t KS2 = 0x1BD11BDAu ^ 42u;   // ks0 = 0

// ---- JAX threefry2x32 (20 rounds), key = PRNGKey(42) = [0, 42] ----
// scalar version (cold/rebuild path)
__device__ __forceinline__ void tf2x32(uint32_t x0, uint32_t x1,
                                       uint32_t& o0, uint32_t& o1) {
  x1 += KS1;
#define TFR(r) { x0 += x1; x1 = rotl32(x1, (r)); x1 ^= x0; }
  TFR(13) TFR(15) TFR(26) TFR(6)
  x0 += KS1; x1 += KS2 + 1u;
  TFR(17) TFR(29) TFR(16) TFR(24)
  x0 += KS2; x1 += 2u;
  TFR(13) TFR(15) TFR(26) TFR(6)
  x1 += KS1 + 3u;
  TFR(17) TFR(29) TFR(16) TFR(24)
  x0 += KS1; x1 += KS2 + 4u;
  TFR(13) TFR(15) TFR(26) TFR(6)
  x0 += KS2; x1 += 5u;
#undef TFR
  o0 = x0; o1 = x1;
}

// 8-wide: 8 independent chains interleaved round-by-round (ILP=8).
// Chains 0-3 hash counters n0+k (quad j), chains 4-7 hash n1+k (quad j+1).
__device__ __forceinline__ void tf8(uint32_t n0, uint32_t n1,
                                    uint32_t (&oa)[8], uint32_t (&ob)[8]) {
  uint32_t x0[8], x1[8];
#pragma unroll
  for (int k = 0; k < 8; ++k) {
    const uint32_t n = (k < 4) ? (n0 + k) : (n1 + (k - 4));
    x0[k] = n; x1[k] = n + (0x2000000u + KS1);
  }
#define R8(r) { _Pragma("unroll") \
  for (int k = 0; k < 8; ++k) { x0[k] += x1[k]; x1[k] = rotl32(x1[k], (r)); x1[k] ^= x0[k]; } }
#define INJ8(a0, a1) { _Pragma("unroll") \
  for (int k = 0; k < 8; ++k) { x0[k] += (a0); x1[k] += (a1); } }
  R8(13) R8(15) R8(26) R8(6)
  INJ8(KS1, KS2 + 1u)
  R8(17) R8(29) R8(16) R8(24)
  INJ8(KS2, 2u)
  R8(13) R8(15) R8(26) R8(6)
  INJ8(0u, KS1 + 3u)
  R8(17) R8(29) R8(16) R8(24)
  INJ8(KS1, KS2 + 4u)
  R8(13) R8(15) R8(26) R8(6)
  INJ8(KS2, 5u)
#undef R8
#undef INJ8
#pragma unroll
  for (int k = 0; k < 8; ++k) { oa[k] = x0[k]; ob[k] = x1[k]; }
}

// full-range 64-bit composite key (rebuild path): larger = better; equal bits
// -> smaller col wins (jax top_k tie-break). Unique per row. 0 = empty.
__device__ __forceinline__ uint64_t mkcomp(uint32_t bits, int c) {
  return (((uint64_t)(bits >> 9) + 1ull) << 14) | (uint64_t)(16383 - c);
}

// branchless thresholded u32 insert, NO label dependency (~10 VALU):
// comp32 = (((o-TH)>>9)+1)<<14 | invc if o>=TH else 0; top-2 via min/max.
__device__ __forceinline__ void filt_ins(uint32_t o, uint32_t invc,
                                         uint32_t& a, uint32_t& b) {
  uint32_t comp = ((((o - TH) >> 9) + 1u) << 14) | invc;
  comp = (o >= TH) ? comp : 0u;
  const uint32_t lo = comp < a ? comp : a;
  a = comp > a ? comp : a;
  b = lo > b ? lo : b;
}

// ---------------- kernel 1: labels + hash + per-thread top-2 ----------------
// Writes cand[r*256+tid] = {L0,L1,H0,H1} and posIdx[r*2+{0,1}] (sorted).
// Positives are NOT excluded from the candidate stream (removed at selection).
__global__ __launch_bounds__(THREADS, 2) void hash_topk(
    const int* __restrict__ lab, uint4* __restrict__ cand,
    int4* __restrict__ posIdx) {
  __shared__ int posCnt[2];
  __shared__ int posBuf[2][4];
  const int tid = threadIdx.x;
  const int r = blockIdx.x;
  const int rbase = r * C;

  if (tid < 2) posCnt[tid] = 0;
  __syncthreads();

  const int4* labL4 = reinterpret_cast<const int4*>(lab + (size_t)rbase);
  const int4* labH4 = reinterpret_cast<const int4*>(lab + ((size_t)r + HALF) * C);
  uint32_t L0 = 0, L1 = 0, H0 = 0, H1 = 0;
  int4 cL0 = labL4[tid],           cH0 = labH4[tid];
  int4 cL1 = labL4[THREADS + tid], cH1 = labH4[THREADS + tid];

#define CAP(V, S, CQ) \
  if (V.x | V.y | V.z | V.w) { \
    if (V.x) { int s = atomicAdd(&posCnt[S], 1); if (s < 4) posBuf[S][s] = (CQ); }     \
    if (V.y) { int s = atomicAdd(&posCnt[S], 1); if (s < 4) posBuf[S][s] = (CQ) + 1; } \
    if (V.z) { int s = atomicAdd(&posCnt[S], 1); if (s < 4) posBuf[S][s] = (CQ) + 2; } \
    if (V.w) { int s = atomicAdd(&posCnt[S], 1); if (s < 4) posBuf[S][s] = (CQ) + 3; } \
  }

#pragma unroll 1
  for (int j = 0; j < QPT; j += 2) {
    int4 nL0 = cL0, nH0 = cH0, nL1 = cL1, nH1 = cH1;
    if (j + 2 < QPT) {                  // prefetch next 2 quads
      nL0 = labL4[(j + 2) * THREADS + tid]; nH0 = labH4[(j + 2) * THREADS + tid];
      nL1 = labL4[(j + 3) * THREADS + tid]; nH1 = labH4[(j + 3) * THREADS + tid];
    }
    const int cq0 = (j * THREADS + tid) << 2;
    const int cq1 = cq0 + (THREADS << 2);
    CAP(cL0, 0, cq0) CAP(cH0, 1, cq0)
    CAP(cL1, 0, cq1) CAP(cH1, 1, cq1)
    uint32_t oa[8], ob[8];
    tf8((uint32_t)(rbase + cq0), (uint32_t)(rbase + cq1), oa, ob);
    const uint32_t i0 = 16383u - (uint32_t)cq0;
    const uint32_t i1 = 16383u - (uint32_t)cq1;
    filt_ins(oa[0], i0,      L0, L1);  filt_ins(oa[1], i0 - 1u, L0, L1);
    filt_ins(oa[2], i0 - 2u, L0, L1);  filt_ins(oa[3], i0 - 3u, L0, L1);
    filt_ins(oa[4], i1,      L0, L1);  filt_ins(oa[5], i1 - 1u, L0, L1);
    filt_ins(oa[6], i1 - 2u, L0, L1);  filt_ins(oa[7], i1 - 3u, L0, L1);
    filt_ins(ob[0], i0,      H0, H1);  filt_ins(ob[1], i0 - 1u, H0, H1);
    filt_ins(ob[2], i0 - 2u, H0, H1);  filt_ins(ob[3], i0 - 3u, H0, H1);
    filt_ins(ob[4], i1,      H0, H1);  filt_ins(ob[5], i1 - 1u, H0, H1);
    filt_ins(ob[6], i1 - 2u, H0, H1);  filt_ins(ob[7], i1 - 3u, H0, H1);
    cL0 = nL0; cH0 = nH0; cL1 = nL1; cH1 = nH1;
  }
#undef CAP

  uint4 st; st.x = L0; st.y = L1; st.z = H0; st.w = H1;
  cand[(size_t)r * THREADS + tid] = st;
  __syncthreads();
  if (tid < 2) {   // sort 4 positive cols ascending (jax top_k tie order)
    int a = posBuf[tid][0], b = posBuf[tid][1], c2 = posBuf[tid][2], d = posBuf[tid][3];
#define CSW(x, y) if (x > y) { int t_ = x; x = y; y = t_; }
    CSW(a, b) CSW(c2, d) CSW(a, c2) CSW(b, d) CSW(b, c2)
#undef CSW
    int4 o; o.x = a; o.y = b; o.z = c2; o.w = d;
    posIdx[r * 2 + tid] = o;
  }
}

// Wave-synchronous top-20-negative selection: pops global-max candidates;
// positive columns are consumed-but-skipped (<=4/row -> <=24 trips total).
// On a thread's cache exhaustion, all 64 lanes cooperatively rescan its 64
// columns (no threshold, no exclusions) for its next comp strictly below
// the last consumed value.
__device__ __forceinline__ void wave_select(
    const uint32_t (*cand)[2], int* selX, int rbase, int hi, int4 p) {
  const int lane = threadIdx.x & 63;
  const int tb = lane << 2;
  const uint64_t laneu = (uint64_t)lane;
#define CVT(x) ((x) ? (uint64_t)(x) + OFF64 : 0ull)
  uint64_t cur0 = CVT(cand[tb + 0][0]), nxt0 = CVT(cand[tb + 0][1]);
  uint64_t cur1 = CVT(cand[tb + 1][0]), nxt1 = CVT(cand[tb + 1][1]);
  uint64_t cur2 = CVT(cand[tb + 2][0]), nxt2 = CVT(cand[tb + 2][1]);
  uint64_t cur3 = CVT(cand[tb + 3][0]), nxt3 = CVT(cand[tb + 3][1]);
#undef CVT
  int got = 0;
#pragma unroll 1
  for (int it = 0; it < NSEL && got < NNEG; ++it) {
    uint64_t m = (cur0 << 8) | laneu;
    uint64_t t = (cur1 << 8) | 0x40ull | laneu; if (t > m) m = t;
    t = (cur2 << 8) | 0x80ull | laneu;          if (t > m) m = t;
    t = (cur3 << 8) | 0xC0ull | laneu;          if (t > m) m = t;
#pragma unroll
    for (int o = 32; o; o >>= 1) {
      const uint64_t y = (uint64_t)__shfl_xor((unsigned long long)m, o, 64);
      if (y > m) m = y;
    }
    const int col = 16383 - (int)((m >> 8) & 0x3FFFull);
    const bool isPos = (col == p.x) || (col == p.y) || (col == p.z) || (col == p.w);
    if (!isPos) {
      if (lane == 0) selX[NPOS + got] = col;
      ++got;
    }
    const int owner = (int)(m & 63ull);
    const int slot  = (int)((m >> 6) & 3ull);
    const uint64_t bound = m >> 8;
    const uint64_t mynxt = slot == 0 ? nxt0 : slot == 1 ? nxt1
                         : slot == 2 ? nxt2 : nxt3;
    const uint64_t ownnxt =
        (uint64_t)__shfl((unsigned long long)mynxt, owner, 64);
    if (ownnxt) {                       // wave-uniform branch
      if (lane == owner) {
        if      (slot == 0) { cur0 = ownnxt; nxt0 = 0; }
        else if (slot == 1) { cur1 = ownnxt; nxt1 = 0; }
        else if (slot == 2) { cur2 = ownnxt; nxt2 = 0; }
        else                { cur3 = ownnxt; nxt3 = 0; }
      }
    } else {                            // cooperative rebuild (rare)
      const int thr = (owner << 2) | slot;
      const int col2 = (((lane >> 2) * THREADS + thr) << 2) + (lane & 3);
      uint32_t o0, o1;
      tf2x32((uint32_t)(rbase + col2), (uint32_t)(rbase + col2) + 0x2000000u, o0, o1);
      uint64_t v = mkcomp(hi ? o1 : o0, col2);
      if (v >= bound) v = 0;
#pragma unroll
      for (int o = 32; o; o >>= 1) {
        const uint64_t y = (uint64_t)__shfl_xor((unsigned long long)v, o, 64);
        if (y > v) v = y;
      }
      if (lane == owner) {
        if      (slot == 0) cur0 = v;
        else if (slot == 1) cur1 = v;
        else if (slot == 2) cur2 = v;
        else                cur3 = v;
      }
    }
  }
}

// ---------------- kernel 2: select + sim + BCE ----------------
__global__ __launch_bounds__(THREADS, 2) void select_sim(
    const float* __restrict__ feat, const float* __restrict__ proto,
    const uint4* __restrict__ cand, const int4* __restrict__ posIdx,
    float* __restrict__ row_ws) {
  __shared__ uint32_t candL[THREADS][2];
  __shared__ uint32_t candH[THREADS][2];
  __shared__ int selL[NSEL], selH[NSEL];
  __shared__ float ffL[D], ffH[D];
  __shared__ float normL, normH;
  __shared__ float bces[2 * NSEL];

  const int tid = threadIdx.x;
  const int r = blockIdx.x;
  const int rbase = r * C;

  const uint4 cd = cand[(size_t)r * THREADS + tid];
  candL[tid][0] = cd.x; candL[tid][1] = cd.y;
  candH[tid][0] = cd.z; candH[tid][1] = cd.w;
  const int4 pL = posIdx[r * 2];
  const int4 pH = posIdx[r * 2 + 1];
  if (tid == 0) { selL[0] = pL.x; selL[1] = pL.y; selL[2] = pL.z; selL[3] = pL.w; }
  if (tid == 1) { selH[0] = pH.x; selH[1] = pH.y; selH[2] = pH.z; selH[3] = pH.w; }
  __syncthreads();

  const int wv = tid >> 6;
  if (wv == 0) {
    wave_select(candL, selL, rbase, 0, pL);
  } else if (wv == 1) {
    wave_select(candH, selH, rbase, 1, pH);
  } else if (wv == 2) {
    const int l = tid & 63;
    const float a = feat[(size_t)r * D + l];
    const float b = feat[(size_t)r * D + 64 + l];
    ffL[l] = a; ffL[64 + l] = b;
    float s = a * a + b * b;
#pragma unroll
    for (int o = 32; o; o >>= 1) s += __shfl_xor(s, o, 64);
    if (l == 0) normL = s;
  } else {
    const int l = tid & 63;
    const float a = feat[((size_t)r + HALF) * D + l];
    const float b = feat[((size_t)r + HALF) * D + 64 + l];
    ffH[l] = a; ffH[64 + l] = b;
    float s = a * a + b * b;
#pragma unroll
    for (int o = 32; o; o >>= 1) s += __shfl_xor(s, o, 64);
    if (l == 0) normH = s;
  }
  __syncthreads();

  if (tid < 4 * 2 * NSEL) {
    const int ci = tid >> 2;            // 0..47
    const int k  = tid & 3;
    const bool isH = ci >= NSEL;
    const int g = isH ? ci - NSEL : ci;
    const int c = isH ? selH[g] : selL[g];
    const float* ff = isH ? ffH : ffL;
    const float4* pc = reinterpret_cast<const float4*>(proto + (size_t)c * D);
    float fp = 0.f, pp = 0.f;
#pragma unroll
    for (int qq = 0; qq < 8; ++qq) {
      const float4 pv = pc[k * 8 + qq];
      const int d0 = k * 32 + qq * 4;
      fp += ff[d0] * pv.x + ff[d0 + 1] * pv.y + ff[d0 + 2] * pv.z + ff[d0 + 3] * pv.w;
      pp += pv.x * pv.x + pv.y * pv.y + pv.z * pv.z + pv.w * pv.w;
    }
    fp += __shfl_xor(fp, 1, 64); pp += __shfl_xor(pp, 1, 64);
    fp += __shfl_xor(fp, 2, 64); pp += __shfl_xor(pp, 2, 64);
    if (k == 0) {
      const float x = (isH ? normH : normL) * pp;
      float rn = rsqrtf(x);
      rn = rn * (1.5f - 0.5f * x * rn * rn);   // 1 NR step for accuracy
      const float l = fp * rn * 10.0f;          // /TEMP, TEMP=0.1
      const float tgt = (g < NPOS) ? 0.25f : 0.0f;
      bces[ci] = fmaxf(l, 0.f) - l * tgt + __logf(1.0f + __expf(-fabsf(l)));
    }
  }
  __syncthreads();
  if (tid < 2) {
    float s = 0.f;
    const int base = tid * NSEL;
#pragma unroll
    for (int i = 0; i < NSEL; ++i) s += bces[base + i];
    row_ws[tid ? (r + HALF) : r] = s * (1.0f / NSEL);
  }
}

__global__ __launch_bounds__(THREADS) void supcon_reduce(
    const float* __restrict__ ws, float* __restrict__ out) {
  __shared__ float red[THREADS];
  const int tid = threadIdx.x;
  float s = 0.f;
#pragma unroll
  for (int j = 0; j < BS / THREADS; ++j) s += ws[j * THREADS + tid];
  red[tid] = s;
  __syncthreads();
  for (int o = THREADS / 2; o > 0; o >>= 1) {
    if (tid < o) red[tid] += red[tid + o];
    __syncthreads();
  }
  if (tid == 0) out[0] = red[0] * (1.0f / BS);
}

extern "C" void kernel_launch(void* const* d_in, const int* in_sizes, int n_in,
                              void* d_out, int out_size, void* d_ws, size_t ws_size,
                              hipStream_t stream) {
  (void)in_sizes; (void)n_in; (void)out_size; (void)ws_size;
  const float* feat  = (const float*)d_in[0];
  const float* proto = (const float*)d_in[1];
  const int*   lab   = (const int*)d_in[2];
  float* out = (float*)d_out;
  // ws layout: [0,16K): row_ws float[4096]; [16K,128K): posIdx int4[4096];
  //            [128K,128K+8M): cand uint4[2048*256]
  float* ws     = (float*)d_ws;
  int4*  posIdx = (int4*)((char*)d_ws + (16 << 10));
  uint4* cand   = (uint4*)((char*)d_ws + (128 << 10));

  hash_topk <<<dim3(HALF), dim3(THREADS), 0, stream>>>(lab, cand, posIdx);
  select_sim<<<dim3(HALF), dim3(THREADS), 0, stream>>>(feat, proto, cand, posIdx, ws);
  supcon_reduce<<<dim3(1), dim3(THREADS), 0, stream>>>(ws, out);
}